// Round 9
// baseline (346.435 us; speedup 1.0000x reference)
//
#include <hip/hip_runtime.h>
#include <stdint.h>

#define DEVI __device__ __forceinline__

typedef __attribute__((ext_vector_type(8))) short short8;
typedef __attribute__((ext_vector_type(4))) float f32x4;
typedef __attribute__((ext_vector_type(4))) uint32_t u32x4;

DEVI unsigned short f2bf(float f) {
    union { float f; uint32_t u; } v; v.f = f;
    return (unsigned short)((v.u + 0x7FFFu + ((v.u >> 16) & 1u)) >> 16);
}

DEVI float bf2f(unsigned short u) {
    union { uint32_t u; float f; } v; v.u = ((uint32_t)u) << 16;
    return v.f;
}

DEVI uint32_t cvtpk_bf16(float a, float b) {
    uint32_t r;
    asm("v_cvt_pk_bf16_f32 %0, %1, %2" : "=v"(r) : "v"(a), "v"(b));
    return r;   // lo16 = bf16(a), hi16 = bf16(b)
}

// D[32:63] <-> S[0:31]
DEVI void perm32(uint32_t &a, uint32_t &b) {
    asm("v_permlane32_swap_b32 %0, %1" : "+v"(a), "+v"(b));
}
// D[16:31] <-> S[0:15], D[48:63] <-> S[32:47]
DEVI void perm16(uint32_t &a, uint32_t &b) {
    asm("v_permlane16_swap_b32 %0, %1" : "+v"(a), "+v"(b));
}

DEVI void gload16(const void* g, void* l) {
    __builtin_amdgcn_global_load_lds(
        (const __attribute__((address_space(1))) unsigned int*)g,
        (__attribute__((address_space(3))) unsigned int*)l, 16, 0, 0);
}

// ---------------- elementwise f32 -> bf16 ----------------
__global__ void k_cvt(const float* __restrict__ in, ushort* __restrict__ out, int n4) {
    int i = blockIdx.x * blockDim.x + threadIdx.x;
    int stride = gridDim.x * blockDim.x;
    for (; i < n4; i += stride) {
        float4 v = ((const float4*)in)[i];
        ushort4 o;
        o.x = f2bf(v.x); o.y = f2bf(v.y); o.z = f2bf(v.z); o.w = f2bf(v.w);
        ((ushort4*)out)[i] = o;
    }
}

// ---------------- transpose + convert: in[R][C] f32 -> out[C][R] bf16 ----------------
__global__ void k_tcvt(const float* __restrict__ in, ushort* __restrict__ out, int R, int C) {
    __shared__ float t[32][33];
    int c0 = blockIdx.x * 32, r0 = blockIdx.y * 32;
    int lr = threadIdx.x >> 5, lc = threadIdx.x & 31;
    #pragma unroll
    for (int i = 0; i < 4; i++)
        t[lr + 8*i][lc] = in[(size_t)(r0 + lr + 8*i)*C + c0 + lc];
    __syncthreads();
    #pragma unroll
    for (int i = 0; i < 4; i++)
        out[(size_t)(c0 + lr + 8*i)*R + r0 + lc] = f2bf(t[lc][lr + 8*i]);
}

// ---------------- GEMM: C[M][N] = A[M][K](bf16) * Bt[N][K]^T(bf16) + bias ----------------
// MODE 0: split epilogue -> Q[B,H,S,64] (pre-scaled by log2e/8), K[B,H,S,64], V^T[B,H,64,S]
// MODE 1: fp32 out [M][N]
template<int MODE>
__global__ __launch_bounds__(256, 2) void k_gemm(
    const ushort* __restrict__ A, const ushort* __restrict__ Bt,
    const float* __restrict__ bias,
    ushort* __restrict__ oQ, ushort* __restrict__ oK, ushort* __restrict__ oV,
    float* __restrict__ oF,
    int M, int N, int K, int S)
{
    __shared__ __align__(16) ushort As[128*64];
    __shared__ __align__(16) ushort Bs[128*64];
    const int tid = threadIdx.x;
    const int w = tid >> 6, l = tid & 63;

    // XCD-aware swizzle (grid sizes are multiples of 8)
    int lin = blockIdx.y * gridDim.x + blockIdx.x;
    int nwg = gridDim.x * gridDim.y;
    int swz = (lin & 7) * (nwg >> 3) + (lin >> 3);
    const int m0 = (swz / gridDim.x) * 128, n0 = (swz % gridDim.x) * 128;

    const int wr = (w >> 1) * 64, wc = (w & 1) * 64;
    const int fr = l & 15, fg = l >> 4;
    const int lr8 = l >> 3;
    const int slot = (l & 7) ^ lr8;   // pre-swizzled global source slot (16B units)

    f32x4 acc[4][4] = {};

    const ushort* Abase = A + (size_t)(m0 + w*32 + lr8) * K + slot*8;
    const ushort* Bbase = Bt + (size_t)(n0 + w*32 + lr8) * K + slot*8;

    for (int k0 = 0; k0 < K; k0 += 64) {
        __syncthreads();
        #pragma unroll
        for (int i = 0; i < 4; i++) {
            gload16(Abase + (size_t)(8*i)*K + k0, &As[(w*32 + 8*i)*64]);
            gload16(Bbase + (size_t)(8*i)*K + k0, &Bs[(w*32 + 8*i)*64]);
        }
        __syncthreads();
        #pragma unroll
        for (int kk = 0; kk < 2; kk++) {
            short8 af[4], bfr[4];
            #pragma unroll
            for (int i = 0; i < 4; i++) {
                int ra = wr + i*16 + fr;
                af[i] = *(const short8*)((const char*)As + ra*128 + ((kk*64 + fg*16) ^ ((ra & 7) << 4)));
                int rb = wc + i*16 + fr;
                bfr[i] = *(const short8*)((const char*)Bs + rb*128 + ((kk*64 + fg*16) ^ ((rb & 7) << 4)));
            }
            #pragma unroll
            for (int i = 0; i < 4; i++)
                #pragma unroll
                for (int j = 0; j < 4; j++)
                    acc[i][j] = __builtin_amdgcn_mfma_f32_16x16x32_bf16(af[i], bfr[j], acc[i][j], 0, 0, 0);
        }
    }

    if (MODE == 1) {
        #pragma unroll
        for (int j = 0; j < 4; j++) {
            int n = n0 + wc + j*16 + fr;
            float bv = bias[n];
            #pragma unroll
            for (int i = 0; i < 4; i++) {
                int mrow = m0 + wr + i*16 + fg*4;
                #pragma unroll
                for (int r = 0; r < 4; r++)
                    oF[(size_t)(mrow + r)*N + n] = acc[i][j][r] + bv;
            }
        }
    } else {
        #pragma unroll
        for (int j = 0; j < 4; j++) {
            int n = n0 + wc + j*16 + fr;
            int region = n >> 10;            // 0=Q 1=K 2=V
            int h = (n & 1023) >> 6;
            int d = n & 63;
            float bv = bias[n];
            float scl = (region == 0) ? 0.18033688011112042f : 1.0f;  // log2(e)/8 folded into Q
            #pragma unroll
            for (int i = 0; i < 4; i++) {
                int mrow = m0 + wr + i*16 + fg*4;
                int b = mrow >> 11;          // / 2048
                int s = mrow & 2047;
                if (region < 2) {
                    ushort* dst = (region == 0 ? oQ : oK) + ((size_t)(b*16 + h)*S)*64 + (size_t)d;
                    #pragma unroll
                    for (int r = 0; r < 4; r++)
                        dst[(size_t)(s + r)*64] = f2bf((acc[i][j][r] + bv) * scl);
                } else {
                    ushort* dst = oV + ((size_t)(b*16 + h)*64 + d)*S + s;
                    ushort4 pk;
                    pk.x = f2bf(acc[i][j][0] + bv);
                    pk.y = f2bf(acc[i][j][1] + bv);
                    pk.z = f2bf(acc[i][j][2] + bv);
                    pk.w = f2bf(acc[i][j][3] + bv);
                    *(ushort4*)dst = pk;
                }
            }
        }
    }
}

// ---------------- flash attention (causal): 1-wave blocks, 4-way KV chunks, full residency ----------------
// 8192 blocks x 64 threads: bid -> (bh = bid&31, w = (bid>>5)&1, rest = bid>>6),
// c = rest&3 (KV quarter), qt = 31-(rest>>2) (heavy-first). 32 waves/CU resident at t=0
// (launch_bounds(64,8), ~60 VGPR). Wave owns 32 q-rows, iterates its KV quarter; K and V
// fragments loaded directly from global (L2-resident). No-max softmax (p = exp2(s),
// additive over chunks); partials (bf16 o, f32 l) -> po/pl; k_comb reduces 4 chunks.
__global__ __launch_bounds__(64, 8) void k_attn(
    const ushort* __restrict__ Q,   // [B,H,S,64] (pre-scaled by log2e/8)
    const ushort* __restrict__ Kb,  // [B,H,S,64]
    const ushort* __restrict__ Vt,  // [B,H,64,S]
    ushort* __restrict__ po,        // [4096][2][2048] bf16 partial O
    float* __restrict__ pl,         // [4096][64]      f32  partial l
    int S)
{
    const int l = threadIdx.x;
    const int bid = blockIdx.x;
    const int bh = bid & 31;
    const int w = (bid >> 5) & 1;
    const int rest = bid >> 6;
    const int c = rest & 3;
    const int qt = 31 - (rest >> 2);     // heavy-first
    const int qw = qt * 64 + w * 32;
    const int fr = l & 15, fg = l >> 4;
    const int obid = (((31 - qt) << 2) | c) * 32 + bh;   // po/pl layout key

    const int len = (qt + 4) >> 2;       // ceil((qt+1)/4)
    int t0 = c * len; if (t0 > qt + 1) t0 = qt + 1;
    int t1 = t0 + len; if (t1 > qt + 1) t1 = qt + 1;

    // Q fragments (B-operand): Q[qw + t*16 + fr][kk*32 + fg*8 + e]
    short8 qf[2][2];
    {
        const ushort* qp = Q + ((size_t)bh*S + qw + fr)*64 + fg*8;
        qf[0][0] = *(const short8*)(qp);
        qf[0][1] = *(const short8*)(qp + 32);
        qf[1][0] = *(const short8*)(qp + 16*64);
        qf[1][1] = *(const short8*)(qp + 16*64 + 32);
    }

    float l_[2] = {0.f, 0.f};
    f32x4 o_[2][4] = {};   // o_[t][f][r] = O[q=qw+t*16+fr][dh=f*16+fg*4+r]

    const ushort* Ksrc = Kb + (size_t)bh*S*64 + (size_t)fr*64 + fg*8;   // + (j0+f*16)*64 (+32 for kk=1)
    const ushort* Vsrc = Vt + (size_t)bh*64*S + (size_t)fr*S + fg*8;    // + (f*16)*S + j0 (+32 for kk=1)

    for (int jt = t0; jt < t1; jt++) {
        const int j0 = jt * 64;

        // V fragments (A-operand) direct from global, issued early:
        // V[f*16+fr][j0+kk*32+fg*8+e]
        short8 vf[2][4];
        #pragma unroll
        for (int kk = 0; kk < 2; kk++)
            #pragma unroll
            for (int f = 0; f < 4; f++)
                vf[kk][f] = *(const short8*)(Vsrc + (size_t)(f*16)*S + j0 + kk*32);

        // K fragments (A-operand) direct from global: K[j0+f*16+fr][kk*32+fg*8+e]
        short8 kf[2][4];
        #pragma unroll
        for (int kk = 0; kk < 2; kk++)
            #pragma unroll
            for (int f = 0; f < 4; f++)
                kf[kk][f] = *(const short8*)(Ksrc + (size_t)(j0 + f*16)*64 + kk*32);

        // QK^T: sa[t][f][r] = S[kv = j0+f*16+fg*4+r][q = qw+t*16+fr]
        f32x4 sa[2][4] = {};
        __builtin_amdgcn_s_setprio(1);
        #pragma unroll
        for (int kk = 0; kk < 2; kk++)
            #pragma unroll
            for (int t = 0; t < 2; t++)
                #pragma unroll
                for (int f = 0; f < 4; f++)
                    sa[t][f] = __builtin_amdgcn_mfma_f32_16x16x32_bf16(kf[kk][f], qf[t][kk], sa[t][f], 0, 0, 0);
        __builtin_amdgcn_s_setprio(0);

        // causal mask (global diagonal tile)
        if (jt == qt) {
            #pragma unroll
            for (int t = 0; t < 2; t++) {
                int qg = qw + t*16 + fr;
                #pragma unroll
                for (int f = 0; f < 4; f++) {
                    int base = j0 + f*16 + fg*4 - qg;
                    #pragma unroll
                    for (int r = 0; r < 4; r++)
                        if (base + r > 0) sa[t][f][r] = -1e30f;
                }
            }
        }

        // no-max softmax: p = exp2(s); lane-partial l; pack to bf16 pairs in-register
        uint32_t cw[2][4][2];
        #pragma unroll
        for (int t = 0; t < 2; t++)
            #pragma unroll
            for (int f = 0; f < 4; f++) {
                float p0 = __builtin_amdgcn_exp2f(sa[t][f][0]);
                float p1 = __builtin_amdgcn_exp2f(sa[t][f][1]);
                float p2 = __builtin_amdgcn_exp2f(sa[t][f][2]);
                float p3 = __builtin_amdgcn_exp2f(sa[t][f][3]);
                l_[t] += (p0 + p1) + (p2 + p3);
                cw[t][f][0] = cvtpk_bf16(p0, p1);
                cw[t][f][1] = cvtpk_bf16(p2, p3);
            }

        // PV: P routed to B-fragments via permlane swaps; V from registers
        #pragma unroll
        for (int kk = 0; kk < 2; kk++) {
            short8 pf[2];
            #pragma unroll
            for (int t = 0; t < 2; t++) {
                uint32_t a0 = cw[t][2*kk][0], b0 = cw[t][2*kk + 1][0];
                perm32(a0, b0); perm16(a0, b0);
                uint32_t a1 = cw[t][2*kk][1], b1 = cw[t][2*kk + 1][1];
                perm32(a1, b1); perm16(a1, b1);
                u32x4 uw; uw[0] = a0; uw[1] = a1; uw[2] = b0; uw[3] = b1;
                pf[t] = __builtin_bit_cast(short8, uw);
            }
            __builtin_amdgcn_s_setprio(1);
            #pragma unroll
            for (int f = 0; f < 4; f++)
                #pragma unroll
                for (int t = 0; t < 2; t++)
                    o_[t][f] = __builtin_amdgcn_mfma_f32_16x16x32_bf16(vf[kk][f], pf[t], o_[t][f], 0, 0, 0);
            __builtin_amdgcn_s_setprio(0);
        }
    }

    // cross-lane l reduce (lanes fr, fr+16, fr+32, fr+48 share a q-row)
    #pragma unroll
    for (int t = 0; t < 2; t++) {
        l_[t] += __shfl_xor(l_[t], 16);
        l_[t] += __shfl_xor(l_[t], 32);
    }

    // write partials (bf16): po[obid][w] + (t*4+f)*256 + fr*16 + fg*4  (ushort units)
    ushort* pob = po + ((size_t)obid * 2 + w) * 2048;
    #pragma unroll
    for (int t = 0; t < 2; t++) {
        #pragma unroll
        for (int f = 0; f < 4; f++) {
            uint2 pk;
            pk.x = cvtpk_bf16(o_[t][f][0], o_[t][f][1]);
            pk.y = cvtpk_bf16(o_[t][f][2], o_[t][f][3]);
            *(uint2*)(pob + (t*4 + f)*256 + fr*16 + fg*4) = pk;
        }
        if (fg == 0) pl[(size_t)obid*64 + w*32 + t*16 + fr] = l_[t];
    }
}

// ---------------- combine: sum 4 chunk partials (bf16), normalize, write bf16 ----------------
__global__ __launch_bounds__(256) void k_comb(
    const ushort* __restrict__ po, const float* __restrict__ pl,
    ushort* __restrict__ O, int S)
{
    const int bx = blockIdx.x;            // [0,1024): qt = bx>>5, bh = bx&31
    const int qt = bx >> 5, bh = bx & 31;
    const int b = bh >> 4, h = bh & 15;
    const int base = ((31 - qt) << 2);    // chunk c -> obid = (base|c)*32 + bh

    #pragma unroll
    for (int k = 0; k < 4; k++) {
        int ss = threadIdx.x + 256 * k;   // [0,1024)
        int w = (ss >> 9) & 1, t = (ss >> 8) & 1, f = (ss >> 6) & 3, fr = (ss >> 2) & 15, fg = ss & 3;
        int g = ss & 511;
        int row = w*32 + t*16 + fr;
        float acc0 = 0.f, acc1 = 0.f, acc2 = 0.f, acc3 = 0.f, den = 0.f;
        #pragma unroll
        for (int c = 0; c < 4; c++) {
            int ob = (base | c) * 32 + bh;
            ushort4 v = *(const ushort4*)(po + ((size_t)ob * 2 + w) * 2048 + g * 4);
            acc0 += bf2f(v.x); acc1 += bf2f(v.y); acc2 += bf2f(v.z); acc3 += bf2f(v.w);
            den += pl[(size_t)ob*64 + row];
        }
        float inv = 1.0f / fmaxf(den, 1e-30f);
        ushort4 pk;
        pk.x = f2bf(acc0 * inv);
        pk.y = f2bf(acc1 * inv);
        pk.z = f2bf(acc2 * inv);
        pk.w = f2bf(acc3 * inv);
        int q = qt*64 + row;
        *(ushort4*)&O[((size_t)(b*S + q))*1024 + h*64 + f*16 + fg*4] = pk;
    }
}

extern "C" void kernel_launch(void* const* d_in, const int* in_sizes, int n_in,
                              void* d_out, int out_size, void* d_ws, size_t ws_size,
                              hipStream_t stream)
{
    const float* x     = (const float*)d_in[0];
    const float* w_in  = (const float*)d_in[1];
    const float* b_in  = (const float*)d_in[2];
    const float* w_out = (const float*)d_in[3];
    const float* b_out = (const float*)d_in[4];
    float* out = (float*)d_out;

    const int B = 2, S = 2048, D = 1024, H = 16;
    const int M = B * S;  // 4096

    if (ws_size < (80u << 20)) return;  // need 80 MB scratch
    char* ws = (char*)d_ws;
    ushort* xb     = (ushort*)(ws);              // 8MB: x bf16, later reused as attn_out
    ushort* w_inT  = (ushort*)(ws + (8u << 20)); // 6MB
    ushort* w_outT = (ushort*)(ws + (14u << 20));// 2MB
    ushort* qb     = (ushort*)(ws + (16u << 20));// 8MB
    ushort* kb     = (ushort*)(ws + (24u << 20));// 8MB
    ushort* vtb    = (ushort*)(ws + (32u << 20));// 8MB
    ushort* po     = (ushort*)(ws + (40u << 20));// 32MB partial O (bf16)
    float*  pl     = (float*)(ws + (73u << 20)); // 1MB partial l

    k_cvt<<<2048, 256, 0, stream>>>(x, xb, M*D/4);
    k_tcvt<<<dim3(3*D/32, D/32), 256, 0, stream>>>(w_in, w_inT, D, 3*D);
    k_tcvt<<<dim3(D/32, D/32), 256, 0, stream>>>(w_out, w_outT, D, D);
    k_gemm<0><<<dim3(3*D/128, M/128), 256, 0, stream>>>(xb, w_inT, b_in, qb, kb, vtb, nullptr, M, 3*D, D, S);
    k_attn<<<8192, 64, 0, stream>>>(qb, kb, vtb, po, pl, S);
    k_comb<<<1024, 256, 0, stream>>>(po, pl, xb, S);
    k_gemm<1><<<dim3(D/128, M/128), 256, 0, stream>>>(xb, w_outT, b_out, nullptr, nullptr, nullptr, out, M, D, D, S);
}

// Round 10
// 107.953 us; speedup vs baseline: 3.2091x; 3.2091x over previous
//
#include <hip/hip_runtime.h>
#include <stdint.h>

#define DEVI __device__ __forceinline__

typedef __attribute__((ext_vector_type(8))) short short8;
typedef __attribute__((ext_vector_type(4))) float f32x4;
typedef __attribute__((ext_vector_type(4))) uint32_t u32x4;

DEVI unsigned short f2bf(float f) {
    union { float f; uint32_t u; } v; v.f = f;
    return (unsigned short)((v.u + 0x7FFFu + ((v.u >> 16) & 1u)) >> 16);
}

DEVI uint32_t cvtpk_bf16(float a, float b) {
    uint32_t r;
    asm("v_cvt_pk_bf16_f32 %0, %1, %2" : "=v"(r) : "v"(a), "v"(b));
    return r;   // lo16 = bf16(a), hi16 = bf16(b)
}

// D[32:63] <-> S[0:31]
DEVI void perm32(uint32_t &a, uint32_t &b) {
    asm("v_permlane32_swap_b32 %0, %1" : "+v"(a), "+v"(b));
}
// D[16:31] <-> S[0:15], D[48:63] <-> S[32:47]
DEVI void perm16(uint32_t &a, uint32_t &b) {
    asm("v_permlane16_swap_b32 %0, %1" : "+v"(a), "+v"(b));
}

DEVI void gload16(const void* g, void* l) {
    __builtin_amdgcn_global_load_lds(
        (const __attribute__((address_space(1))) unsigned int*)g,
        (__attribute__((address_space(3))) unsigned int*)l, 16, 0, 0);
}

// ---------------- elementwise f32 -> bf16 ----------------
__global__ void k_cvt(const float* __restrict__ in, ushort* __restrict__ out, int n4) {
    int i = blockIdx.x * blockDim.x + threadIdx.x;
    int stride = gridDim.x * blockDim.x;
    for (; i < n4; i += stride) {
        float4 v = ((const float4*)in)[i];
        ushort4 o;
        o.x = f2bf(v.x); o.y = f2bf(v.y); o.z = f2bf(v.z); o.w = f2bf(v.w);
        ((ushort4*)out)[i] = o;
    }
}

// ---------------- transpose + convert: in[R][C] f32 -> out[C][R] bf16 ----------------
__global__ void k_tcvt(const float* __restrict__ in, ushort* __restrict__ out, int R, int C) {
    __shared__ float t[32][33];
    int c0 = blockIdx.x * 32, r0 = blockIdx.y * 32;
    int lr = threadIdx.x >> 5, lc = threadIdx.x & 31;
    #pragma unroll
    for (int i = 0; i < 4; i++)
        t[lr + 8*i][lc] = in[(size_t)(r0 + lr + 8*i)*C + c0 + lc];
    __syncthreads();
    #pragma unroll
    for (int i = 0; i < 4; i++)
        out[(size_t)(c0 + lr + 8*i)*R + r0 + lc] = f2bf(t[lc][lr + 8*i]);
}

// ---------------- GEMM: C[M][BNgrid] = A[M][K](bf16) * Bt[N][K]^T(bf16) + bias ----------------
// Tile: 128 x (NJ*32). NJ=4 -> 128x128 (4 waves x 64x64); NJ=2 -> 128x64 (4 waves x 64x32).
// MODE 0: split epilogue -> Q[B,H,S,64] (pre-scaled by log2e/8), K[B,H,S,64], V^T[B,H,64,S]
// MODE 1: fp32 out [M][N]
template<int MODE, int NJ>
__global__ __launch_bounds__(256, 2) void k_gemm(
    const ushort* __restrict__ A, const ushort* __restrict__ Bt,
    const float* __restrict__ bias,
    ushort* __restrict__ oQ, ushort* __restrict__ oK, ushort* __restrict__ oV,
    float* __restrict__ oF,
    int M, int N, int K, int S)
{
    __shared__ __align__(16) ushort As[128*64];
    __shared__ __align__(16) ushort Bs[NJ*32*64];
    const int tid = threadIdx.x;
    const int w = tid >> 6, l = tid & 63;

    // XCD-aware swizzle (grid sizes are multiples of 8)
    int lin = blockIdx.y * gridDim.x + blockIdx.x;
    int nwg = gridDim.x * gridDim.y;
    int swz = (lin & 7) * (nwg >> 3) + (lin >> 3);
    const int m0 = (swz / gridDim.x) * 128, n0 = (swz % gridDim.x) * (NJ*32);

    const int wr = (w >> 1) * 64, wc = (w & 1) * (NJ*16);
    const int fr = l & 15, fg = l >> 4;
    const int lr8 = l >> 3;
    const int slot = (l & 7) ^ lr8;   // pre-swizzled global source slot (16B units)

    f32x4 acc[4][NJ] = {};

    const ushort* Abase = A + (size_t)(m0 + w*32 + lr8) * K + slot*8;
    const ushort* Bbase = Bt + (size_t)(n0 + w*(NJ*8) + lr8) * K + slot*8;

    for (int k0 = 0; k0 < K; k0 += 64) {
        __syncthreads();
        #pragma unroll
        for (int i = 0; i < 4; i++)
            gload16(Abase + (size_t)(8*i)*K + k0, &As[(w*32 + 8*i)*64]);
        #pragma unroll
        for (int i = 0; i < NJ; i++)
            gload16(Bbase + (size_t)(8*i)*K + k0, &Bs[(w*(NJ*8) + 8*i)*64]);
        __syncthreads();
        #pragma unroll
        for (int kk = 0; kk < 2; kk++) {
            short8 af[4], bfr[NJ];
            #pragma unroll
            for (int i = 0; i < 4; i++) {
                int ra = wr + i*16 + fr;
                af[i] = *(const short8*)((const char*)As + ra*128 + ((kk*64 + fg*16) ^ ((ra & 7) << 4)));
            }
            #pragma unroll
            for (int j = 0; j < NJ; j++) {
                int rb = wc + j*16 + fr;
                bfr[j] = *(const short8*)((const char*)Bs + rb*128 + ((kk*64 + fg*16) ^ ((rb & 7) << 4)));
            }
            #pragma unroll
            for (int i = 0; i < 4; i++)
                #pragma unroll
                for (int j = 0; j < NJ; j++)
                    acc[i][j] = __builtin_amdgcn_mfma_f32_16x16x32_bf16(af[i], bfr[j], acc[i][j], 0, 0, 0);
        }
    }

    if (MODE == 1) {
        #pragma unroll
        for (int j = 0; j < NJ; j++) {
            int n = n0 + wc + j*16 + fr;
            float bv = bias[n];
            #pragma unroll
            for (int i = 0; i < 4; i++) {
                int mrow = m0 + wr + i*16 + fg*4;
                #pragma unroll
                for (int r = 0; r < 4; r++)
                    oF[(size_t)(mrow + r)*N + n] = acc[i][j][r] + bv;
            }
        }
    } else {
        #pragma unroll
        for (int j = 0; j < NJ; j++) {
            int n = n0 + wc + j*16 + fr;
            int region = n >> 10;            // 0=Q 1=K 2=V
            int h = (n & 1023) >> 6;
            int d = n & 63;
            float bv = bias[n];
            float scl = (region == 0) ? 0.18033688011112042f : 1.0f;  // log2(e)/8 folded into Q
            #pragma unroll
            for (int i = 0; i < 4; i++) {
                int mrow = m0 + wr + i*16 + fg*4;
                int b = mrow >> 11;          // / 2048
                int s = mrow & 2047;
                if (region < 2) {
                    ushort* dst = (region == 0 ? oQ : oK) + ((size_t)(b*16 + h)*S)*64 + (size_t)d;
                    #pragma unroll
                    for (int r = 0; r < 4; r++)
                        dst[(size_t)(s + r)*64] = f2bf((acc[i][j][r] + bv) * scl);
                } else {
                    ushort* dst = oV + ((size_t)(b*16 + h)*64 + d)*S + s;
                    ushort4 pk;
                    pk.x = f2bf(acc[i][j][0] + bv);
                    pk.y = f2bf(acc[i][j][1] + bv);
                    pk.z = f2bf(acc[i][j][2] + bv);
                    pk.w = f2bf(acc[i][j][3] + bv);
                    *(ushort4*)dst = pk;
                }
            }
        }
    }
}

// ---------------- flash attention (causal), swapped-operand, no-max, P-in-register ----------------
// 2-wave blocks, BQ=64 (32 rows/wave), BKV=64, double-buffered K/V, permlane P routing (no P LDS).
// (R4-proven configuration: 42.4 us)
__global__ __launch_bounds__(128, 2) void k_attn(
    const ushort* __restrict__ Q,   // [B,H,S,64] (pre-scaled by log2e/8)
    const ushort* __restrict__ Kb,  // [B,H,S,64]
    const ushort* __restrict__ Vt,  // [B,H,64,S]
    ushort* __restrict__ O,         // [B*S][1024] bf16
    int S)
{
    __shared__ __align__(16) ushort Kt[2][64*64];
    __shared__ __align__(16) ushort Vs[2][64*64];

    const int tid = threadIdx.x, w = tid >> 6, l = tid & 63;
    const int bid = blockIdx.x;
    const int half = bid >> 9;           // heavy-first + complementary pairing
    const int r_ = bid & 511;
    const int h = r_ & 15, b = (r_ >> 4) & 1, p = r_ >> 5;   // p in [0,16)
    const int qt = half ? p : (31 - p);  // bids 0..511 -> qt 16..31 (heavy, dispatched first)
    const int bh = b * 16 + h;
    const int qw = qt * 64 + w * 32;
    const int fr = l & 15, fg = l >> 4;

    // Q fragments (B-operand): Q[qw + t*16 + fr][kk*32 + fg*8 + e]
    short8 qf[2][2];
    {
        const ushort* qp = Q + ((size_t)bh*S + qw + fr)*64 + fg*8;
        qf[0][0] = *(const short8*)(qp);
        qf[0][1] = *(const short8*)(qp + 32);
        qf[1][0] = *(const short8*)(qp + 16*64);
        qf[1][1] = *(const short8*)(qp + 16*64 + 32);
    }

    float l_[2] = {0.f, 0.f};
    f32x4 o_[2][4] = {};   // o_[t][f][r] = O[q=qw+t*16+fr][dh=f*16+fg*4+r]

    const int lr8 = l >> 3;
    const int slot = (l & 7) ^ lr8;
    const ushort* Ksrc = Kb + (size_t)bh*S*64;
    const ushort* Vsrc = Vt + (size_t)bh*64*S;

    const int nt = qt + 1;

    auto stage = [&](int buf, int j0) {
        #pragma unroll
        for (int i = 0; i < 4; i++) {
            int rb = w*32 + i*8;
            gload16(Ksrc + (size_t)(j0 + rb + lr8)*64 + slot*8, &Kt[buf][rb*64]);
            gload16(Vsrc + (size_t)(rb + lr8)*S + j0 + slot*8, &Vs[buf][rb*64]);
        }
    };

    stage(0, 0);
    __syncthreads();
    int cur = 0;

    for (int jt = 0; jt < nt; jt++) {
        const int j0 = jt * 64;
        if (jt + 1 < nt) stage(cur ^ 1, j0 + 64);

        // QK^T: sa[t][f][r] = S[kv = j0+f*16+fg*4+r][q = qw+t*16+fr]
        f32x4 sa[2][4] = {};
        __builtin_amdgcn_s_setprio(1);
        #pragma unroll
        for (int kk = 0; kk < 2; kk++) {
            short8 kf[4];
            #pragma unroll
            for (int f = 0; f < 4; f++) {
                int row = f*16 + fr;
                kf[f] = *(const short8*)((const char*)Kt[cur] + row*128 + ((kk*64 + fg*16) ^ ((row & 7) << 4)));
            }
            #pragma unroll
            for (int t = 0; t < 2; t++)
                #pragma unroll
                for (int f = 0; f < 4; f++)
                    sa[t][f] = __builtin_amdgcn_mfma_f32_16x16x32_bf16(kf[f], qf[t][kk], sa[t][f], 0, 0, 0);
        }
        __builtin_amdgcn_s_setprio(0);

        // causal mask (diagonal tile only)
        if (jt == nt - 1) {
            #pragma unroll
            for (int t = 0; t < 2; t++) {
                int qg = qw + t*16 + fr;
                #pragma unroll
                for (int f = 0; f < 4; f++) {
                    int base = j0 + f*16 + fg*4 - qg;
                    #pragma unroll
                    for (int r = 0; r < 4; r++)
                        if (base + r > 0) sa[t][f][r] = -1e30f;
                }
            }
        }

        // no-max softmax: p = exp2(s); lane-partial l; pack to bf16 pairs in-register
        uint32_t cw[2][4][2];   // cw[t][f][rr] : bf16 pair (kv = f*16+fg*4+2rr, +1)
        #pragma unroll
        for (int t = 0; t < 2; t++)
            #pragma unroll
            for (int f = 0; f < 4; f++) {
                float p0 = __builtin_amdgcn_exp2f(sa[t][f][0]);
                float p1 = __builtin_amdgcn_exp2f(sa[t][f][1]);
                float p2 = __builtin_amdgcn_exp2f(sa[t][f][2]);
                float p3 = __builtin_amdgcn_exp2f(sa[t][f][3]);
                l_[t] += (p0 + p1) + (p2 + p3);
                cw[t][f][0] = cvtpk_bf16(p0, p1);
                cw[t][f][1] = cvtpk_bf16(p2, p3);
            }

        // PV: route P to B-fragments via permlane32/16 swaps (2 ops -> 2 words), then MFMA
        __builtin_amdgcn_s_setprio(1);
        #pragma unroll
        for (int kk = 0; kk < 2; kk++) {
            short8 pf[2];
            #pragma unroll
            for (int t = 0; t < 2; t++) {
                uint32_t a0 = cw[t][2*kk][0], b0 = cw[t][2*kk + 1][0];
                perm32(a0, b0); perm16(a0, b0);   // a0 = word0, b0 = word2
                uint32_t a1 = cw[t][2*kk][1], b1 = cw[t][2*kk + 1][1];
                perm32(a1, b1); perm16(a1, b1);   // a1 = word1, b1 = word3
                u32x4 uw; uw[0] = a0; uw[1] = a1; uw[2] = b0; uw[3] = b1;
                pf[t] = __builtin_bit_cast(short8, uw);
            }
            #pragma unroll
            for (int f = 0; f < 4; f++) {
                int row = f*16 + fr;
                short8 vf = *(const short8*)((const char*)Vs[cur] + row*128 + ((kk*64 + fg*16) ^ ((row & 7) << 4)));
                #pragma unroll
                for (int t = 0; t < 2; t++)
                    o_[t][f] = __builtin_amdgcn_mfma_f32_16x16x32_bf16(vf, pf[t], o_[t][f], 0, 0, 0);
            }
        }
        __builtin_amdgcn_s_setprio(0);

        __syncthreads();   // drains vmcnt(0) for prefetched stage + barrier
        cur ^= 1;
    }

    // cross-lane l reduce (lanes fr, fr+16, fr+32, fr+48 share a q-row)
    #pragma unroll
    for (int t = 0; t < 2; t++) {
        l_[t] += __shfl_xor(l_[t], 16);
        l_[t] += __shfl_xor(l_[t], 32);
    }

    // epilogue: O[b*S + q][h*64 + dh], 4 consecutive dh per store
    #pragma unroll
    for (int t = 0; t < 2; t++) {
        float inv = 1.0f / l_[t];
        int qg = qw + t*16 + fr;
        #pragma unroll
        for (int f = 0; f < 4; f++) {
            ushort4 pk;
            pk.x = f2bf(o_[t][f][0] * inv);
            pk.y = f2bf(o_[t][f][1] * inv);
            pk.z = f2bf(o_[t][f][2] * inv);
            pk.w = f2bf(o_[t][f][3] * inv);
            *(ushort4*)&O[((size_t)(b*S + qg))*1024 + h*64 + f*16 + fg*4] = pk;
        }
    }
}

extern "C" void kernel_launch(void* const* d_in, const int* in_sizes, int n_in,
                              void* d_out, int out_size, void* d_ws, size_t ws_size,
                              hipStream_t stream)
{
    const float* x     = (const float*)d_in[0];
    const float* w_in  = (const float*)d_in[1];
    const float* b_in  = (const float*)d_in[2];
    const float* w_out = (const float*)d_in[3];
    const float* b_out = (const float*)d_in[4];
    float* out = (float*)d_out;

    const int B = 2, S = 2048, D = 1024, H = 16;
    const int M = B * S;  // 4096

    if (ws_size < (40u << 20)) return;  // need 40 MB scratch
    char* ws = (char*)d_ws;
    ushort* xb     = (ushort*)(ws);              // 8MB: x bf16, later reused as attn_out
    ushort* w_inT  = (ushort*)(ws + (8u << 20)); // 6MB
    ushort* w_outT = (ushort*)(ws + (14u << 20));// 2MB
    ushort* qb     = (ushort*)(ws + (16u << 20));// 8MB
    ushort* kb     = (ushort*)(ws + (24u << 20));// 8MB
    ushort* vtb    = (ushort*)(ws + (32u << 20));// 8MB

    k_cvt<<<2048, 256, 0, stream>>>(x, xb, M*D/4);
    k_tcvt<<<dim3(3*D/32, D/32), 256, 0, stream>>>(w_in, w_inT, D, 3*D);
    k_tcvt<<<dim3(D/32, D/32), 256, 0, stream>>>(w_out, w_outT, D, D);
    k_gemm<0,4><<<dim3(3*D/128, M/128), 256, 0, stream>>>(xb, w_inT, b_in, qb, kb, vtb, nullptr, M, 3*D, D, S);
    k_attn<<<1024, 128, 0, stream>>>(qb, kb, vtb, xb, S);
    k_gemm<1,2><<<dim3(D/64, M/128), 256, 0, stream>>>(xb, w_outT, b_out, nullptr, nullptr, nullptr, out, M, D, D, S);
}